// Round 4
// baseline (1182.555 us; speedup 1.0000x reference)
//
#include <hip/hip_runtime.h>
#include <math.h>

#define NPTS 4096
#define NB 2
#define K_TOTAL 12
#define BLOCK 256
#define TILE 128
#define NT (NPTS / TILE)   // 32 tile-blocks per dimension

// ws layout (floats / 4B words):
//  [0..24)    sched: 12 x {eps, w}
//  [32..48)   Mbuf (unsigned, monotone-encoded float max): 2 slots x 8 (pot,batch)
//  [64..)     P: 4 pots x NB x NPTS   (f_ba, g_ab, f_aa, g_bb)
//  [..)       PART: per-(pot,batch) x 32 slots x 4096 partial sums (no atomics)
#define SCHED_OFF 0
#define MBUF_OFF 32
#define P_OFF 64
#define POT_SZ (4 * NB * NPTS)
#define PART_OFF (P_OFF + POT_SZ)
// part[pb][slot][i]: pb in [0,8), slot in [0,NT), i in [0,NPTS)

#if __has_builtin(__builtin_amdgcn_exp2f)
#define EXP2F __builtin_amdgcn_exp2f
#else
#define EXP2F exp2f
#endif
#if __has_builtin(__builtin_amdgcn_logf)
#define LOG2F __builtin_amdgcn_logf
#else
#define LOG2F log2f
#endif
#if __has_builtin(__builtin_amdgcn_sqrtf)
#define FSQRTF __builtin_amdgcn_sqrtf
#else
#define FSQRTF sqrtf
#endif

#define BASE_LOGW -8.31776616671934f  // -log(4096), N==M
#define LOG2E 1.4426950408889634f
#define LN2 0.69314718055994531f

// monotone float<->uint encoding so unsigned atomicMax == float max
__device__ __forceinline__ unsigned encf(float f) {
  unsigned u = __float_as_uint(f);
  return (u & 0x80000000u) ? ~u : (u | 0x80000000u);
}
__device__ __forceinline__ float decf(unsigned k) {
  return __uint_as_float((k & 0x80000000u) ? (k ^ 0x80000000u) : ~k);
}

// ---------------------------------------------------------------------------
// Kernel A (grid=64): block 0 computes diameter (f32, matching numpy) +
// eps schedule (f64, matching np.arange/np.exp) + Mbuf slots;
// blocks 1..63 zero P. (No S/V arrays exist anymore.)
// ---------------------------------------------------------------------------
__global__ __launch_bounds__(BLOCK) void k_init(
    const float2* __restrict__ x, const float2* __restrict__ y, float* ws)
{
  const int tid = threadIdx.x;
  const int bid = blockIdx.x;

  if (bid > 0) {
    for (int i = (bid - 1) * BLOCK + tid; i < POT_SZ; i += 63 * BLOCK)
      ws[P_OFF + i] = 0.0f;
    return;
  }

  if (tid < 8) {
    unsigned* MB = (unsigned*)ws + MBUF_OFF;
    MB[8 + tid] = encf(BASE_LOGW);  // slot 1: M_{-1} (P=0 -> h=logw -> V=1)
    MB[tid] = encf(-1e30f);         // slot 0: target of step-0 combine
  }

  float mnx = 1e30f, mny = 1e30f, mxx = -1e30f, mxy = -1e30f;
  for (int i = tid; i < NB * NPTS; i += BLOCK) {
    float2 p = x[i];
    mnx = fminf(mnx, p.x); mxx = fmaxf(mxx, p.x);
    mny = fminf(mny, p.y); mxy = fmaxf(mxy, p.y);
    float2 q = y[i];
    mnx = fminf(mnx, q.x); mxx = fmaxf(mxx, q.x);
    mny = fminf(mny, q.y); mxy = fmaxf(mxy, q.y);
  }
  for (int o = 32; o; o >>= 1) {
    mnx = fminf(mnx, __shfl_xor(mnx, o, 64));
    mxx = fmaxf(mxx, __shfl_xor(mxx, o, 64));
    mny = fminf(mny, __shfl_xor(mny, o, 64));
    mxy = fmaxf(mxy, __shfl_xor(mxy, o, 64));
  }
  __shared__ float r[4][4];
  const int wave = tid >> 6, lane = tid & 63;
  if (lane == 0) { r[0][wave] = mnx; r[1][wave] = mxx; r[2][wave] = mny; r[3][wave] = mxy; }
  __syncthreads();
  if (tid == 0) {
    mnx = fminf(fminf(r[0][0], r[0][1]), fminf(r[0][2], r[0][3]));
    mxx = fmaxf(fmaxf(r[1][0], r[1][1]), fmaxf(r[1][2], r[1][3]));
    mny = fminf(fminf(r[2][0], r[2][1]), fminf(r[2][2], r[2][3]));
    mxy = fmaxf(fmaxf(r[3][0], r[3][1]), fmaxf(r[3][2], r[3][3]));
    float rx = mxx - mnx, ry = mxy - mny;
    float dia = sqrtf(rx * rx + ry * ry);

    double a = log((double)dia);
    double stop = log(0.05);
    double stp = log(0.5);
    int cnt = (int)ceil((stop - a) / stp);  // data: cnt == 8
    if (cnt < 0) cnt = 0;
    if (cnt > K_TOTAL - 4) cnt = K_TOTAL - 4;

    float* sch = ws + SCHED_OFF;
    sch[0] = dia; sch[1] = 0.0f;   // init: direct assign at eps=diameter
    sch[2] = dia; sch[3] = 0.5f;   // loop over eps_list, w=0.5
    for (int k = 0; k < cnt; k++) {
      sch[2 * (2 + k)] = (float)exp(a + (double)k * stp);
      sch[2 * (2 + k) + 1] = 0.5f;
    }
    sch[2 * (2 + cnt)] = 0.05f; sch[2 * (2 + cnt) + 1] = 0.5f;
    for (int s = 3 + cnt; s < K_TOTAL - 1; s++) { sch[2 * s] = 0.05f; sch[2 * s + 1] = 1.0f; }
    sch[2 * (K_TOTAL - 1)] = 0.05f; sch[2 * (K_TOTAL - 1) + 1] = 0.0f;  // final extrapolation
  }
}

// ---------------------------------------------------------------------------
// Kernel B: K-tile sweep, NO GLOBAL ATOMICS. Each block owns a 128x128 tile;
// V built on the fly at staging from P + M. Inner entry: 2 sub, mul+fma,
// sqrt, exp2(-t), 2 acc-fma. Epilogue: LDS transpose (reused [16][129]
// buffer) -> 128-lane partial sums -> plain coalesced stores into
// part[pb][slot][.] where slot = the OTHER tile coordinate:
//   row sums  -> part[pb_row][tj][ti*128 ..]
//   col sums  -> part[pb_col][ti][tj*128 ..]   (dual blocks only)
// Each (pb,slot,i) cell is written by exactly one block -> race-free.
// blocks: [0, 2048) cross; [2048, 6144) self (ti>tj exit early).
// Block 0 also resets this step's Mbuf slot for k_combine's atomicMax.
// ---------------------------------------------------------------------------
__global__ __launch_bounds__(BLOCK, 8) void k_tiles(
    const float2* __restrict__ xpts, const float2* __restrict__ ypts,
    float* __restrict__ ws, int stepi)
{
  __shared__ float rXs[TILE], rYs[TILE], rVs[TILE];
  __shared__ float cXs[144], cYs[144], cVs[144];  // padded: idx + idx/8
  __shared__ float tPart[16][129];                // reused for rows then cols

  const int tid = threadIdx.x;
  const int id = blockIdx.x;

  const float2* rowp; const float2* colp;
  const float* prow; const float* pcol;
  int ti, tj, pbr, pbc;
  bool dual;

  if (id < NB * NT * NT) {
    const int b = id >> 10;
    const int t = id & (NT * NT - 1);
    ti = t >> 5; tj = t & (NT - 1);
    rowp = xpts + b * NPTS; colp = ypts + b * NPTS;
    prow = ws + P_OFF + (0 * NB + b) * NPTS;  // P0 = f_ba drives row-side V
    pcol = ws + P_OFF + (1 * NB + b) * NPTS;  // P1 = g_ab drives col-side V
    pbr = 0 * NB + b; pbc = 1 * NB + b;
    dual = true;
  } else {
    const int id2 = id - NB * NT * NT;
    const int mat = id2 >> 11;      // 0: C_xx, 1: C_yy
    const int t2 = id2 & 2047;
    const int b = t2 >> 10;
    const int t = t2 & 1023;
    ti = t >> 5; tj = t & 31;
    if (ti > tj) return;            // symmetric: upper triangle only
    const float2* pts = mat ? ypts : xpts;
    rowp = pts + b * NPTS; colp = rowp;
    const int p = 2 + mat;
    prow = ws + P_OFF + (p * NB + b) * NPTS; pcol = prow;
    pbr = p * NB + b; pbc = pbr;
    dual = (ti != tj);              // diagonal tile: row sums only
  }

  const float eps = ws[SCHED_OFF + 2 * stepi];
  const float sc = LOG2E / eps;     // exp2(-sqrt(d2_scaled)) = e^{-d/eps}
  const float inv_eps = 1.0f / eps; // h = logw + P/eps (this step's V)
  const unsigned* MB = (const unsigned*)ws + MBUF_OFF + 8 * ((stepi + 1) & 1);

  if (id == 0 && tid < 8)           // reset the OTHER slot for this step's combine
    ((unsigned*)ws)[MBUF_OFF + 8 * (stepi & 1) + tid] = encf(-1e30f);

  if (tid < TILE) {
    const int r = ti * TILE + tid;
    float2 pr = rowp[r];
    float h = fmaf(prow[r], inv_eps, BASE_LOGW);
    rXs[tid] = pr.x * sc; rYs[tid] = pr.y * sc;
    rVs[tid] = EXP2F((h - decf(MB[pbr])) * LOG2E);
  } else {
    const int k = tid - TILE;
    const int r = tj * TILE + k;
    float2 pc = colp[r];
    float h = fmaf(pcol[r], inv_eps, BASE_LOGW);
    const int kk = k + (k >> 3);    // pad to break 4-way preload conflict
    cXs[kk] = pc.x * sc; cYs[kk] = pc.y * sc;
    cVs[kk] = EXP2F((h - decf(MB[pbc])) * LOG2E);
  }
  __syncthreads();

  const int tx = tid & 15, ty = tid >> 4;
  float rx[8], ry[8], rv[8], cx[8], cy[8], cv[8], racc[8], cacc[8];
#pragma unroll
  for (int q = 0; q < 8; q++) {
    rx[q] = rXs[ty * 8 + q]; ry[q] = rYs[ty * 8 + q]; rv[q] = rVs[ty * 8 + q];
    const int ci = tx * 9 + q;      // (tx*8+q) padded
    cx[q] = cXs[ci]; cy[q] = cYs[ci]; cv[q] = cVs[ci];
    racc[q] = 0.0f; cacc[q] = 0.0f;
  }

#pragma unroll
  for (int q = 0; q < 8; q++) {
#pragma unroll
    for (int p = 0; p < 8; p++) {
      float dx = rx[q] - cx[p];
      float dy = ry[q] - cy[p];
      float t = FSQRTF(fmaf(dx, dx, dy * dy));
      float K = EXP2F(-t);          // neg is a free src modifier
      racc[q] = fmaf(K, cv[p], racc[q]);
      cacc[p] = fmaf(K, rv[q], cacc[p]);
    }
  }

  float* part = ws + PART_OFF;

  // rows: transpose via LDS, 128-lane sum, plain store to slot tj
#pragma unroll
  for (int q = 0; q < 8; q++) tPart[tx][ty * 8 + q] = racc[q];
  __syncthreads();
  if (tid < TILE) {
    float s = 0.0f;
#pragma unroll
    for (int t = 0; t < 16; t++) s += tPart[t][tid];
    part[(pbr * NT + tj) * NPTS + ti * TILE + tid] = s;
  }
  __syncthreads();

  // cols: same buffer, slot ti
#pragma unroll
  for (int q = 0; q < 8; q++) tPart[ty][tx * 8 + q] = cacc[q];
  __syncthreads();
  if (dual && tid < TILE) {
    float s = 0.0f;
#pragma unroll
    for (int t = 0; t < 16; t++) s += tPart[t][tid];
    part[(pbc * NT + ti) * NPTS + tj * TILE + tid] = s;
  }
}

// ---------------------------------------------------------------------------
// Kernel C (grid=128: 8 pb x 16 chunks): S = sum of 32 slot partials,
// finalize f, mix with w, write P in place, atomicMax new h-max into this
// step's Mbuf slot. No S zeroing needed (partials fully rewritten).
// ---------------------------------------------------------------------------
__global__ __launch_bounds__(BLOCK) void k_combine(float* __restrict__ ws, int stepi)
{
  const int bid = blockIdx.x;
  const int pb = bid >> 4, chunk = bid & 15;
  const int tid = threadIdx.x;

  const float eps = ws[SCHED_OFF + 2 * stepi];
  const float w = ws[SCHED_OFF + 2 * stepi + 1];
  int ni = stepi + 1; if (ni > K_TOTAL - 1) ni = K_TOTAL - 1;
  const float inv_eps_n = 1.0f / ws[SCHED_OFF + 2 * ni];
  unsigned* MB = (unsigned*)ws + MBUF_OFF;
  const float Mh = decf(MB[8 * ((stepi + 1) & 1) + pb]);  // M used in this step's V

  const int r = chunk * BLOCK + tid;
  const float* pp = ws + PART_OFF + pb * NT * NPTS + r;
  float s = 0.0f;
#pragma unroll
  for (int c = 0; c < NT; c++) s += pp[c * NPTS];

  float* Pp = ws + P_OFF + pb * NPTS;
  s = fmaxf(s, 1e-37f);
  float ft = -eps * fmaf(LN2, LOG2F(s), Mh);
  float fo = Pp[r];
  float fn = (w >= 1.0f) ? fo : fmaf(w, fo, (1.0f - w) * ft);
  Pp[r] = fn;
  float lmax = fmaf(fn, inv_eps_n, BASE_LOGW);  // h for next step

  for (int o = 32; o; o >>= 1) lmax = fmaxf(lmax, __shfl_xor(lmax, o, 64));
  __shared__ float red[4];
  if ((tid & 63) == 0) red[tid >> 6] = lmax;
  __syncthreads();
  if (tid == 0) {
    float M = fmaxf(fmaxf(red[0], red[1]), fmaxf(red[2], red[3]));
    atomicMax(&MB[8 * (stepi & 1) + pb], encf(M));
  }
}

// ---------------------------------------------------------------------------
// Kernel D: out = mean_b [ (1/N) sum(f_ba - f_aa) + (1/M) sum(g_ab - g_bb) ]
// ---------------------------------------------------------------------------
__global__ __launch_bounds__(1024) void k_reduce(
    const float* __restrict__ pot, float* __restrict__ out)
{
  const int tid = threadIdx.x;
  double acc = 0.0;
  for (int i = tid; i < POT_SZ; i += 1024) {
    double v = (double)pot[i];
    acc += (i < 2 * NB * NPTS) ? v : -v;  // +f_ba +g_ab -f_aa -g_bb
  }
  for (int o = 32; o; o >>= 1) acc += __shfl_xor(acc, o, 64);
  __shared__ double rd[16];
  const int wave = tid >> 6, lane = tid & 63;
  if (lane == 0) rd[wave] = acc;
  __syncthreads();
  if (tid == 0) {
    double s = 0.0;
#pragma unroll
    for (int i = 0; i < 16; i++) s += rd[i];
    out[0] = (float)(s / (double)(NB * NPTS));
  }
}

extern "C" void kernel_launch(void* const* d_in, const int* in_sizes, int n_in,
                              void* d_out, int out_size, void* d_ws, size_t ws_size,
                              hipStream_t stream)
{
  const float2* x = (const float2*)d_in[0];  // pre (2,4096,2)
  const float2* y = (const float2*)d_in[1];  // gt  (2,4096,2)
  float* ws = (float*)d_ws;

  k_init<<<64, BLOCK, 0, stream>>>(x, y, ws);

  const int nblocks = NB * NT * NT + 2 * NB * NT * NT;  // 2048 cross + 4096 self
  for (int s = 0; s < K_TOTAL; s++) {
    k_tiles<<<nblocks, BLOCK, 0, stream>>>(x, y, ws, s);
    k_combine<<<128, BLOCK, 0, stream>>>(ws, s);
  }
  k_reduce<<<1, 1024, 0, stream>>>(ws + P_OFF, (float*)d_out);
}

// Round 5
// 518.889 us; speedup vs baseline: 2.2790x; 2.2790x over previous
//
#include <hip/hip_runtime.h>
#include <math.h>

#define NPTS 4096
#define NB 2
#define K_TOTAL 12
#define BLOCK 256
#define TILE 128
#define NT (NPTS / TILE)   // 32 tile-blocks per dimension

// ws layout (floats / 4B words):
//  [0..24)    sched: 12 x {eps, w}
//  [32..48)   Mbuf (unsigned, monotone-encoded float max): 2 slots x 8 (pot,batch)
//  [64..)     P: 4 pots x NB x NPTS   (f_ba, g_ab, f_aa, g_bb)
//  [..)       PART: per-(pot,batch) x 32 slots x 4096 partial sums (no atomics)
#define SCHED_OFF 0
#define MBUF_OFF 32
#define P_OFF 64
#define POT_SZ (4 * NB * NPTS)
#define PART_OFF (P_OFF + POT_SZ)
// part[pb][slot][i]: pb in [0,8), slot in [0,NT), i in [0,NPTS)

#if __has_builtin(__builtin_amdgcn_exp2f)
#define EXP2F __builtin_amdgcn_exp2f
#else
#define EXP2F exp2f
#endif
#if __has_builtin(__builtin_amdgcn_logf)
#define LOG2F __builtin_amdgcn_logf
#else
#define LOG2F log2f
#endif
#if __has_builtin(__builtin_amdgcn_sqrtf)
#define FSQRTF __builtin_amdgcn_sqrtf
#else
#define FSQRTF sqrtf
#endif

#define BASE_LOGW -8.31776616671934f  // -log(4096), N==M
#define LOG2E 1.4426950408889634f
#define LN2 0.69314718055994531f

// monotone float<->uint encoding so unsigned atomicMax == float max
__device__ __forceinline__ unsigned encf(float f) {
  unsigned u = __float_as_uint(f);
  return (u & 0x80000000u) ? ~u : (u | 0x80000000u);
}
__device__ __forceinline__ float decf(unsigned k) {
  return __uint_as_float((k & 0x80000000u) ? (k ^ 0x80000000u) : ~k);
}

// ---------------------------------------------------------------------------
// Kernel A (grid=64): block 0 computes diameter (f32, matching numpy) +
// eps schedule (f64, matching np.arange/np.exp) + Mbuf slots;
// blocks 1..63 zero P. (No S/V arrays exist anymore.)
// ---------------------------------------------------------------------------
__global__ __launch_bounds__(BLOCK) void k_init(
    const float2* __restrict__ x, const float2* __restrict__ y, float* ws)
{
  const int tid = threadIdx.x;
  const int bid = blockIdx.x;

  if (bid > 0) {
    for (int i = (bid - 1) * BLOCK + tid; i < POT_SZ; i += 63 * BLOCK)
      ws[P_OFF + i] = 0.0f;
    return;
  }

  if (tid < 8) {
    unsigned* MB = (unsigned*)ws + MBUF_OFF;
    MB[8 + tid] = encf(BASE_LOGW);  // slot 1: M_{-1} (P=0 -> h=logw -> V=1)
    MB[tid] = encf(-1e30f);         // slot 0: target of step-0 combine
  }

  float mnx = 1e30f, mny = 1e30f, mxx = -1e30f, mxy = -1e30f;
  for (int i = tid; i < NB * NPTS; i += BLOCK) {
    float2 p = x[i];
    mnx = fminf(mnx, p.x); mxx = fmaxf(mxx, p.x);
    mny = fminf(mny, p.y); mxy = fmaxf(mxy, p.y);
    float2 q = y[i];
    mnx = fminf(mnx, q.x); mxx = fmaxf(mxx, q.x);
    mny = fminf(mny, q.y); mxy = fmaxf(mxy, q.y);
  }
  for (int o = 32; o; o >>= 1) {
    mnx = fminf(mnx, __shfl_xor(mnx, o, 64));
    mxx = fmaxf(mxx, __shfl_xor(mxx, o, 64));
    mny = fminf(mny, __shfl_xor(mny, o, 64));
    mxy = fmaxf(mxy, __shfl_xor(mxy, o, 64));
  }
  __shared__ float r[4][4];
  const int wave = tid >> 6, lane = tid & 63;
  if (lane == 0) { r[0][wave] = mnx; r[1][wave] = mxx; r[2][wave] = mny; r[3][wave] = mxy; }
  __syncthreads();
  if (tid == 0) {
    mnx = fminf(fminf(r[0][0], r[0][1]), fminf(r[0][2], r[0][3]));
    mxx = fmaxf(fmaxf(r[1][0], r[1][1]), fmaxf(r[1][2], r[1][3]));
    mny = fminf(fminf(r[2][0], r[2][1]), fminf(r[2][2], r[2][3]));
    mxy = fmaxf(fmaxf(r[3][0], r[3][1]), fmaxf(r[3][2], r[3][3]));
    float rx = mxx - mnx, ry = mxy - mny;
    float dia = sqrtf(rx * rx + ry * ry);

    double a = log((double)dia);
    double stop = log(0.05);
    double stp = log(0.5);
    int cnt = (int)ceil((stop - a) / stp);  // data: cnt == 8
    if (cnt < 0) cnt = 0;
    if (cnt > K_TOTAL - 4) cnt = K_TOTAL - 4;

    float* sch = ws + SCHED_OFF;
    sch[0] = dia; sch[1] = 0.0f;   // init: direct assign at eps=diameter
    sch[2] = dia; sch[3] = 0.5f;   // loop over eps_list, w=0.5
    for (int k = 0; k < cnt; k++) {
      sch[2 * (2 + k)] = (float)exp(a + (double)k * stp);
      sch[2 * (2 + k) + 1] = 0.5f;
    }
    sch[2 * (2 + cnt)] = 0.05f; sch[2 * (2 + cnt) + 1] = 0.5f;
    for (int s = 3 + cnt; s < K_TOTAL - 1; s++) { sch[2 * s] = 0.05f; sch[2 * s + 1] = 1.0f; }
    sch[2 * (K_TOTAL - 1)] = 0.05f; sch[2 * (K_TOTAL - 1) + 1] = 0.0f;  // final extrapolation
  }
}

// ---------------------------------------------------------------------------
// Kernel B: K-tile sweep, NO GLOBAL ATOMICS. Each block owns a 128x128 tile;
// V built on the fly at staging from P + M. Inner entry: 2 sub, mul+fma,
// sqrt, exp2(-t), 2 acc-fma. Epilogue: LDS transpose (reused [16][129]
// buffer) -> 128-lane partial sums -> plain coalesced stores into
// part[pb][slot][.] where slot = the OTHER tile coordinate:
//   row sums  -> part[pb_row][tj][ti*128 ..]
//   col sums  -> part[pb_col][ti][tj*128 ..]   (dual blocks only)
// Each (pb,slot,i) cell is written by exactly one block -> race-free.
// blocks: [0, 2048) cross; [2048, 6144) self (ti>tj exit early).
// Block 0 also resets this step's Mbuf slot for k_combine's atomicMax.
// launch_bounds (256,4): VGPR cap 128 -- inner loop needs ~80 live floats;
// (256,8) capped at 32 VGPR and spilled ~300MB/dispatch to scratch (round 4).
// ---------------------------------------------------------------------------
__global__ __launch_bounds__(BLOCK, 4) void k_tiles(
    const float2* __restrict__ xpts, const float2* __restrict__ ypts,
    float* __restrict__ ws, int stepi)
{
  __shared__ float rXs[TILE], rYs[TILE], rVs[TILE];
  __shared__ float cXs[144], cYs[144], cVs[144];  // padded: idx + idx/8
  __shared__ float tPart[16][129];                // reused for rows then cols

  const int tid = threadIdx.x;
  const int id = blockIdx.x;

  const float2* rowp; const float2* colp;
  const float* prow; const float* pcol;
  int ti, tj, pbr, pbc;
  bool dual;

  if (id < NB * NT * NT) {
    const int b = id >> 10;
    const int t = id & (NT * NT - 1);
    ti = t >> 5; tj = t & (NT - 1);
    rowp = xpts + b * NPTS; colp = ypts + b * NPTS;
    prow = ws + P_OFF + (0 * NB + b) * NPTS;  // P0 = f_ba drives row-side V
    pcol = ws + P_OFF + (1 * NB + b) * NPTS;  // P1 = g_ab drives col-side V
    pbr = 0 * NB + b; pbc = 1 * NB + b;
    dual = true;
  } else {
    const int id2 = id - NB * NT * NT;
    const int mat = id2 >> 11;      // 0: C_xx, 1: C_yy
    const int t2 = id2 & 2047;
    const int b = t2 >> 10;
    const int t = t2 & 1023;
    ti = t >> 5; tj = t & 31;
    if (ti > tj) return;            // symmetric: upper triangle only
    const float2* pts = mat ? ypts : xpts;
    rowp = pts + b * NPTS; colp = rowp;
    const int p = 2 + mat;
    prow = ws + P_OFF + (p * NB + b) * NPTS; pcol = prow;
    pbr = p * NB + b; pbc = pbr;
    dual = (ti != tj);              // diagonal tile: row sums only
  }

  const float eps = ws[SCHED_OFF + 2 * stepi];
  const float sc = LOG2E / eps;     // exp2(-sqrt(d2_scaled)) = e^{-d/eps}
  const float inv_eps = 1.0f / eps; // h = logw + P/eps (this step's V)
  const unsigned* MB = (const unsigned*)ws + MBUF_OFF + 8 * ((stepi + 1) & 1);

  if (id == 0 && tid < 8)           // reset the OTHER slot for this step's combine
    ((unsigned*)ws)[MBUF_OFF + 8 * (stepi & 1) + tid] = encf(-1e30f);

  if (tid < TILE) {
    const int r = ti * TILE + tid;
    float2 pr = rowp[r];
    float h = fmaf(prow[r], inv_eps, BASE_LOGW);
    rXs[tid] = pr.x * sc; rYs[tid] = pr.y * sc;
    rVs[tid] = EXP2F((h - decf(MB[pbr])) * LOG2E);
  } else {
    const int k = tid - TILE;
    const int r = tj * TILE + k;
    float2 pc = colp[r];
    float h = fmaf(pcol[r], inv_eps, BASE_LOGW);
    const int kk = k + (k >> 3);    // pad to break 4-way preload conflict
    cXs[kk] = pc.x * sc; cYs[kk] = pc.y * sc;
    cVs[kk] = EXP2F((h - decf(MB[pbc])) * LOG2E);
  }
  __syncthreads();

  const int tx = tid & 15, ty = tid >> 4;
  float rx[8], ry[8], rv[8], cx[8], cy[8], cv[8], racc[8], cacc[8];
#pragma unroll
  for (int q = 0; q < 8; q++) {
    rx[q] = rXs[ty * 8 + q]; ry[q] = rYs[ty * 8 + q]; rv[q] = rVs[ty * 8 + q];
    const int ci = tx * 9 + q;      // (tx*8+q) padded
    cx[q] = cXs[ci]; cy[q] = cYs[ci]; cv[q] = cVs[ci];
    racc[q] = 0.0f; cacc[q] = 0.0f;
  }

#pragma unroll
  for (int q = 0; q < 8; q++) {
#pragma unroll
    for (int p = 0; p < 8; p++) {
      float dx = rx[q] - cx[p];
      float dy = ry[q] - cy[p];
      float t = FSQRTF(fmaf(dx, dx, dy * dy));
      float K = EXP2F(-t);          // neg is a free src modifier
      racc[q] = fmaf(K, cv[p], racc[q]);
      cacc[p] = fmaf(K, rv[q], cacc[p]);
    }
  }

  float* part = ws + PART_OFF;

  // rows: transpose via LDS, 128-lane sum, plain store to slot tj
#pragma unroll
  for (int q = 0; q < 8; q++) tPart[tx][ty * 8 + q] = racc[q];
  __syncthreads();
  if (tid < TILE) {
    float s = 0.0f;
#pragma unroll
    for (int t = 0; t < 16; t++) s += tPart[t][tid];
    part[(pbr * NT + tj) * NPTS + ti * TILE + tid] = s;
  }
  __syncthreads();

  // cols: same buffer, slot ti
#pragma unroll
  for (int q = 0; q < 8; q++) tPart[ty][tx * 8 + q] = cacc[q];
  __syncthreads();
  if (dual && tid < TILE) {
    float s = 0.0f;
#pragma unroll
    for (int t = 0; t < 16; t++) s += tPart[t][tid];
    part[(pbc * NT + ti) * NPTS + tj * TILE + tid] = s;
  }
}

// ---------------------------------------------------------------------------
// Kernel C (grid=128: 8 pb x 16 chunks): S = sum of 32 slot partials,
// finalize f, mix with w, write P in place, atomicMax new h-max into this
// step's Mbuf slot. No S zeroing needed (partials fully rewritten).
// ---------------------------------------------------------------------------
__global__ __launch_bounds__(BLOCK) void k_combine(float* __restrict__ ws, int stepi)
{
  const int bid = blockIdx.x;
  const int pb = bid >> 4, chunk = bid & 15;
  const int tid = threadIdx.x;

  const float eps = ws[SCHED_OFF + 2 * stepi];
  const float w = ws[SCHED_OFF + 2 * stepi + 1];
  int ni = stepi + 1; if (ni > K_TOTAL - 1) ni = K_TOTAL - 1;
  const float inv_eps_n = 1.0f / ws[SCHED_OFF + 2 * ni];
  unsigned* MB = (unsigned*)ws + MBUF_OFF;
  const float Mh = decf(MB[8 * ((stepi + 1) & 1) + pb]);  // M used in this step's V

  const int r = chunk * BLOCK + tid;
  const float* pp = ws + PART_OFF + pb * NT * NPTS + r;
  float s = 0.0f;
#pragma unroll
  for (int c = 0; c < NT; c++) s += pp[c * NPTS];

  float* Pp = ws + P_OFF + pb * NPTS;
  s = fmaxf(s, 1e-37f);
  float ft = -eps * fmaf(LN2, LOG2F(s), Mh);
  float fo = Pp[r];
  float fn = (w >= 1.0f) ? fo : fmaf(w, fo, (1.0f - w) * ft);
  Pp[r] = fn;
  float lmax = fmaf(fn, inv_eps_n, BASE_LOGW);  // h for next step

  for (int o = 32; o; o >>= 1) lmax = fmaxf(lmax, __shfl_xor(lmax, o, 64));
  __shared__ float red[4];
  if ((tid & 63) == 0) red[tid >> 6] = lmax;
  __syncthreads();
  if (tid == 0) {
    float M = fmaxf(fmaxf(red[0], red[1]), fmaxf(red[2], red[3]));
    atomicMax(&MB[8 * (stepi & 1) + pb], encf(M));
  }
}

// ---------------------------------------------------------------------------
// Kernel D: out = mean_b [ (1/N) sum(f_ba - f_aa) + (1/M) sum(g_ab - g_bb) ]
// ---------------------------------------------------------------------------
__global__ __launch_bounds__(1024) void k_reduce(
    const float* __restrict__ pot, float* __restrict__ out)
{
  const int tid = threadIdx.x;
  double acc = 0.0;
  for (int i = tid; i < POT_SZ; i += 1024) {
    double v = (double)pot[i];
    acc += (i < 2 * NB * NPTS) ? v : -v;  // +f_ba +g_ab -f_aa -g_bb
  }
  for (int o = 32; o; o >>= 1) acc += __shfl_xor(acc, o, 64);
  __shared__ double rd[16];
  const int wave = tid >> 6, lane = tid & 63;
  if (lane == 0) rd[wave] = acc;
  __syncthreads();
  if (tid == 0) {
    double s = 0.0;
#pragma unroll
    for (int i = 0; i < 16; i++) s += rd[i];
    out[0] = (float)(s / (double)(NB * NPTS));
  }
}

extern "C" void kernel_launch(void* const* d_in, const int* in_sizes, int n_in,
                              void* d_out, int out_size, void* d_ws, size_t ws_size,
                              hipStream_t stream)
{
  const float2* x = (const float2*)d_in[0];  // pre (2,4096,2)
  const float2* y = (const float2*)d_in[1];  // gt  (2,4096,2)
  float* ws = (float*)d_ws;

  k_init<<<64, BLOCK, 0, stream>>>(x, y, ws);

  const int nblocks = NB * NT * NT + 2 * NB * NT * NT;  // 2048 cross + 4096 self
  for (int s = 0; s < K_TOTAL; s++) {
    k_tiles<<<nblocks, BLOCK, 0, stream>>>(x, y, ws, s);
    k_combine<<<128, BLOCK, 0, stream>>>(ws, s);
  }
  k_reduce<<<1, 1024, 0, stream>>>(ws + P_OFF, (float*)d_out);
}

// Round 6
// 445.587 us; speedup vs baseline: 2.6539x; 1.1645x over previous
//
#include <hip/hip_runtime.h>
#include <math.h>

#define NPTS 4096
#define NB 2
#define K_TOTAL 12
#define BLOCK 256
#define TILE 128
#define NT (NPTS / TILE)   // 32 tile-blocks per dimension

// ws layout (floats / 4B words):
//  [0..24)    sched: 12 x {eps, w}
//  [32..48)   Mbuf (unsigned, monotone-encoded float max): 2 slots x 8 (pot,batch)
//  [64..)     P: 4 pots x NB x NPTS   (f_ba, g_ab, f_aa, g_bb)
//  [..)       PART: per-(pot,batch) x 32 slots x 4096 partial sums (no atomics)
#define SCHED_OFF 0
#define MBUF_OFF 32
#define P_OFF 64
#define POT_SZ (4 * NB * NPTS)
#define PART_OFF (P_OFF + POT_SZ)
// part[pb][slot][i]: pb in [0,8), slot in [0,NT), i in [0,NPTS)

#if __has_builtin(__builtin_amdgcn_exp2f)
#define EXP2F __builtin_amdgcn_exp2f
#else
#define EXP2F exp2f
#endif
#if __has_builtin(__builtin_amdgcn_logf)
#define LOG2F __builtin_amdgcn_logf
#else
#define LOG2F log2f
#endif
#if __has_builtin(__builtin_amdgcn_sqrtf)
#define FSQRTF __builtin_amdgcn_sqrtf
#else
#define FSQRTF sqrtf
#endif

#define BASE_LOGW -8.31776616671934f  // -log(4096), N==M
#define LOG2E 1.4426950408889634f
#define LN2 0.69314718055994531f

typedef float v2f __attribute__((ext_vector_type(2)));

// monotone float<->uint encoding so unsigned atomicMax == float max
__device__ __forceinline__ unsigned encf(float f) {
  unsigned u = __float_as_uint(f);
  return (u & 0x80000000u) ? ~u : (u | 0x80000000u);
}
__device__ __forceinline__ float decf(unsigned k) {
  return __uint_as_float((k & 0x80000000u) ? (k ^ 0x80000000u) : ~k);
}

// ---------------------------------------------------------------------------
// Kernel A (grid=64): block 0 computes diameter (f32, matching numpy) +
// eps schedule (f64, matching np.arange/np.exp) + Mbuf slots;
// blocks 1..63 zero P. (No S/V arrays exist anymore.)
// ---------------------------------------------------------------------------
__global__ __launch_bounds__(BLOCK) void k_init(
    const float2* __restrict__ x, const float2* __restrict__ y, float* ws)
{
  const int tid = threadIdx.x;
  const int bid = blockIdx.x;

  if (bid > 0) {
    for (int i = (bid - 1) * BLOCK + tid; i < POT_SZ; i += 63 * BLOCK)
      ws[P_OFF + i] = 0.0f;
    return;
  }

  if (tid < 8) {
    unsigned* MB = (unsigned*)ws + MBUF_OFF;
    MB[8 + tid] = encf(BASE_LOGW);  // slot 1: M_{-1} (P=0 -> h=logw -> V=1)
    MB[tid] = encf(-1e30f);         // slot 0: target of step-0 combine
  }

  float mnx = 1e30f, mny = 1e30f, mxx = -1e30f, mxy = -1e30f;
  for (int i = tid; i < NB * NPTS; i += BLOCK) {
    float2 p = x[i];
    mnx = fminf(mnx, p.x); mxx = fmaxf(mxx, p.x);
    mny = fminf(mny, p.y); mxy = fmaxf(mxy, p.y);
    float2 q = y[i];
    mnx = fminf(mnx, q.x); mxx = fmaxf(mxx, q.x);
    mny = fminf(mny, q.y); mxy = fmaxf(mxy, q.y);
  }
  for (int o = 32; o; o >>= 1) {
    mnx = fminf(mnx, __shfl_xor(mnx, o, 64));
    mxx = fmaxf(mxx, __shfl_xor(mxx, o, 64));
    mny = fminf(mny, __shfl_xor(mny, o, 64));
    mxy = fmaxf(mxy, __shfl_xor(mxy, o, 64));
  }
  __shared__ float r[4][4];
  const int wave = tid >> 6, lane = tid & 63;
  if (lane == 0) { r[0][wave] = mnx; r[1][wave] = mxx; r[2][wave] = mny; r[3][wave] = mxy; }
  __syncthreads();
  if (tid == 0) {
    mnx = fminf(fminf(r[0][0], r[0][1]), fminf(r[0][2], r[0][3]));
    mxx = fmaxf(fmaxf(r[1][0], r[1][1]), fmaxf(r[1][2], r[1][3]));
    mny = fminf(fminf(r[2][0], r[2][1]), fminf(r[2][2], r[2][3]));
    mxy = fmaxf(fmaxf(r[3][0], r[3][1]), fmaxf(r[3][2], r[3][3]));
    float rx = mxx - mnx, ry = mxy - mny;
    float dia = sqrtf(rx * rx + ry * ry);

    double a = log((double)dia);
    double stop = log(0.05);
    double stp = log(0.5);
    int cnt = (int)ceil((stop - a) / stp);  // data: cnt == 8
    if (cnt < 0) cnt = 0;
    if (cnt > K_TOTAL - 4) cnt = K_TOTAL - 4;

    float* sch = ws + SCHED_OFF;
    sch[0] = dia; sch[1] = 0.0f;   // init: direct assign at eps=diameter
    sch[2] = dia; sch[3] = 0.5f;   // loop over eps_list, w=0.5
    for (int k = 0; k < cnt; k++) {
      sch[2 * (2 + k)] = (float)exp(a + (double)k * stp);
      sch[2 * (2 + k) + 1] = 0.5f;
    }
    sch[2 * (2 + cnt)] = 0.05f; sch[2 * (2 + cnt) + 1] = 0.5f;
    for (int s = 3 + cnt; s < K_TOTAL - 1; s++) { sch[2 * s] = 0.05f; sch[2 * s + 1] = 1.0f; }
    sch[2 * (K_TOTAL - 1)] = 0.05f; sch[2 * (K_TOTAL - 1) + 1] = 0.0f;  // final extrapolation
  }
}

// ---------------------------------------------------------------------------
// Kernel B: K-tile sweep, NO GLOBAL ATOMICS, PACKED-F32 inner loop.
// Each block owns a 128x128 tile; V built on the fly at staging from P + M.
// Column pairs processed as float2 (v_pk_add/mul/fma_f32 on gfx950):
//   per 2 entries: 4 pk dist ops + 2 scalar sqrt + 2 scalar exp2 + 2 pk fma
//   => ~14 issue cyc/entry vs 20 scalar.
// Epilogue: LDS transpose (reused [16][129]) -> 128-lane partial sums ->
// plain coalesced stores into part[pb][slot][.] (slot = other tile coord):
//   row sums  -> part[pb_row][tj][ti*128 ..]
//   col sums  -> part[pb_col][ti][tj*128 ..]   (dual blocks only)
// Each (pb,slot,i) cell written by exactly one block -> race-free.
// blocks: [0, 2048) cross; [2048, 6144) self (ti>tj exit early).
// launch_bounds (256,4): VGPR cap 128 -- (256,8) capped at 32 and spilled
// ~300MB/dispatch to scratch (round 4). Packed accs add ~8 VGPRs, still fits.
// ---------------------------------------------------------------------------
__global__ __launch_bounds__(BLOCK, 4) void k_tiles(
    const float2* __restrict__ xpts, const float2* __restrict__ ypts,
    float* __restrict__ ws, int stepi)
{
  __shared__ float rXs[TILE], rYs[TILE], rVs[TILE];
  __shared__ float cXs[144], cYs[144], cVs[144];  // padded: idx + idx/8
  __shared__ float tPart[16][129];                // reused for rows then cols

  const int tid = threadIdx.x;
  const int id = blockIdx.x;

  const float2* rowp; const float2* colp;
  const float* prow; const float* pcol;
  int ti, tj, pbr, pbc;
  bool dual;

  if (id < NB * NT * NT) {
    const int b = id >> 10;
    const int t = id & (NT * NT - 1);
    ti = t >> 5; tj = t & (NT - 1);
    rowp = xpts + b * NPTS; colp = ypts + b * NPTS;
    prow = ws + P_OFF + (0 * NB + b) * NPTS;  // P0 = f_ba drives row-side V
    pcol = ws + P_OFF + (1 * NB + b) * NPTS;  // P1 = g_ab drives col-side V
    pbr = 0 * NB + b; pbc = 1 * NB + b;
    dual = true;
  } else {
    const int id2 = id - NB * NT * NT;
    const int mat = id2 >> 11;      // 0: C_xx, 1: C_yy
    const int t2 = id2 & 2047;
    const int b = t2 >> 10;
    const int t = t2 & 1023;
    ti = t >> 5; tj = t & 31;
    if (ti > tj) return;            // symmetric: upper triangle only
    const float2* pts = mat ? ypts : xpts;
    rowp = pts + b * NPTS; colp = rowp;
    const int p = 2 + mat;
    prow = ws + P_OFF + (p * NB + b) * NPTS; pcol = prow;
    pbr = p * NB + b; pbc = pbr;
    dual = (ti != tj);              // diagonal tile: row sums only
  }

  const float eps = ws[SCHED_OFF + 2 * stepi];
  const float sc = LOG2E / eps;     // exp2(-sqrt(d2_scaled)) = e^{-d/eps}
  const float inv_eps = 1.0f / eps; // h = logw + P/eps (this step's V)
  const unsigned* MB = (const unsigned*)ws + MBUF_OFF + 8 * ((stepi + 1) & 1);

  if (id == 0 && tid < 8)           // reset the OTHER slot for this step's combine
    ((unsigned*)ws)[MBUF_OFF + 8 * (stepi & 1) + tid] = encf(-1e30f);

  if (tid < TILE) {
    const int r = ti * TILE + tid;
    float2 pr = rowp[r];
    float h = fmaf(prow[r], inv_eps, BASE_LOGW);
    rXs[tid] = pr.x * sc; rYs[tid] = pr.y * sc;
    rVs[tid] = EXP2F((h - decf(MB[pbr])) * LOG2E);
  } else {
    const int k = tid - TILE;
    const int r = tj * TILE + k;
    float2 pc = colp[r];
    float h = fmaf(pcol[r], inv_eps, BASE_LOGW);
    const int kk = k + (k >> 3);    // pad to break 4-way preload conflict
    cXs[kk] = pc.x * sc; cYs[kk] = pc.y * sc;
    cVs[kk] = EXP2F((h - decf(MB[pbc])) * LOG2E);
  }
  __syncthreads();

  const int tx = tid & 15, ty = tid >> 4;
  float rx[8], ry[8], rv[8];
  v2f cx2[4], cy2[4], cv2[4], racc2[8], cacc2[4];
#pragma unroll
  for (int q = 0; q < 8; q++) {
    rx[q] = rXs[ty * 8 + q]; ry[q] = rYs[ty * 8 + q]; rv[q] = rVs[ty * 8 + q];
    racc2[q] = (v2f){0.0f, 0.0f};
  }
#pragma unroll
  for (int j = 0; j < 4; j++) {
    const int ci = tx * 9 + 2 * j;  // padded (tx*8 + 2j); pairs stay adjacent
    cx2[j] = (v2f){cXs[ci], cXs[ci + 1]};
    cy2[j] = (v2f){cYs[ci], cYs[ci + 1]};
    cv2[j] = (v2f){cVs[ci], cVs[ci + 1]};
    cacc2[j] = (v2f){0.0f, 0.0f};
  }

#pragma unroll
  for (int q = 0; q < 8; q++) {
    const v2f rxq = (v2f){rx[q], rx[q]};
    const v2f ryq = (v2f){ry[q], ry[q]};
    const v2f rvq = (v2f){rv[q], rv[q]};
#pragma unroll
    for (int j = 0; j < 4; j++) {
      v2f dx = rxq - cx2[j];        // v_pk_add_f32
      v2f dy = ryq - cy2[j];
      v2f d2 = dx * dx + dy * dy;   // v_pk_mul + v_pk_fma
      float t0 = FSQRTF(d2.x), t1 = FSQRTF(d2.y);
      v2f K = (v2f){EXP2F(-t0), EXP2F(-t1)};
      racc2[q] += K * cv2[j];       // v_pk_fma
      cacc2[j] += K * rvq;          // v_pk_fma
    }
  }

  float* part = ws + PART_OFF;

  // rows: transpose via LDS, 128-lane sum, plain store to slot tj
#pragma unroll
  for (int q = 0; q < 8; q++) tPart[tx][ty * 8 + q] = racc2[q].x + racc2[q].y;
  __syncthreads();
  if (tid < TILE) {
    float s = 0.0f;
#pragma unroll
    for (int t = 0; t < 16; t++) s += tPart[t][tid];
    part[(pbr * NT + tj) * NPTS + ti * TILE + tid] = s;
  }
  __syncthreads();

  // cols: same buffer, slot ti
#pragma unroll
  for (int j = 0; j < 4; j++) {
    tPart[ty][tx * 8 + 2 * j] = cacc2[j].x;
    tPart[ty][tx * 8 + 2 * j + 1] = cacc2[j].y;
  }
  __syncthreads();
  if (dual && tid < TILE) {
    float s = 0.0f;
#pragma unroll
    for (int t = 0; t < 16; t++) s += tPart[t][tid];
    part[(pbc * NT + ti) * NPTS + tj * TILE + tid] = s;
  }
}

// ---------------------------------------------------------------------------
// Kernel C (grid=128: 8 pb x 16 chunks): S = sum of 32 slot partials,
// finalize f, mix with w, write P in place, atomicMax new h-max into this
// step's Mbuf slot. No S zeroing needed (partials fully rewritten).
// ---------------------------------------------------------------------------
__global__ __launch_bounds__(BLOCK) void k_combine(float* __restrict__ ws, int stepi)
{
  const int bid = blockIdx.x;
  const int pb = bid >> 4, chunk = bid & 15;
  const int tid = threadIdx.x;

  const float eps = ws[SCHED_OFF + 2 * stepi];
  const float w = ws[SCHED_OFF + 2 * stepi + 1];
  int ni = stepi + 1; if (ni > K_TOTAL - 1) ni = K_TOTAL - 1;
  const float inv_eps_n = 1.0f / ws[SCHED_OFF + 2 * ni];
  unsigned* MB = (unsigned*)ws + MBUF_OFF;
  const float Mh = decf(MB[8 * ((stepi + 1) & 1) + pb]);  // M used in this step's V

  const int r = chunk * BLOCK + tid;
  const float* pp = ws + PART_OFF + pb * NT * NPTS + r;
  float s = 0.0f;
#pragma unroll
  for (int c = 0; c < NT; c++) s += pp[c * NPTS];

  float* Pp = ws + P_OFF + pb * NPTS;
  s = fmaxf(s, 1e-37f);
  float ft = -eps * fmaf(LN2, LOG2F(s), Mh);
  float fo = Pp[r];
  float fn = (w >= 1.0f) ? fo : fmaf(w, fo, (1.0f - w) * ft);
  Pp[r] = fn;
  float lmax = fmaf(fn, inv_eps_n, BASE_LOGW);  // h for next step

  for (int o = 32; o; o >>= 1) lmax = fmaxf(lmax, __shfl_xor(lmax, o, 64));
  __shared__ float red[4];
  if ((tid & 63) == 0) red[tid >> 6] = lmax;
  __syncthreads();
  if (tid == 0) {
    float M = fmaxf(fmaxf(red[0], red[1]), fmaxf(red[2], red[3]));
    atomicMax(&MB[8 * (stepi & 1) + pb], encf(M));
  }
}

// ---------------------------------------------------------------------------
// Kernel D: out = mean_b [ (1/N) sum(f_ba - f_aa) + (1/M) sum(g_ab - g_bb) ]
// ---------------------------------------------------------------------------
__global__ __launch_bounds__(1024) void k_reduce(
    const float* __restrict__ pot, float* __restrict__ out)
{
  const int tid = threadIdx.x;
  double acc = 0.0;
  for (int i = tid; i < POT_SZ; i += 1024) {
    double v = (double)pot[i];
    acc += (i < 2 * NB * NPTS) ? v : -v;  // +f_ba +g_ab -f_aa -g_bb
  }
  for (int o = 32; o; o >>= 1) acc += __shfl_xor(acc, o, 64);
  __shared__ double rd[16];
  const int wave = tid >> 6, lane = tid & 63;
  if (lane == 0) rd[wave] = acc;
  __syncthreads();
  if (tid == 0) {
    double s = 0.0;
#pragma unroll
    for (int i = 0; i < 16; i++) s += rd[i];
    out[0] = (float)(s / (double)(NB * NPTS));
  }
}

extern "C" void kernel_launch(void* const* d_in, const int* in_sizes, int n_in,
                              void* d_out, int out_size, void* d_ws, size_t ws_size,
                              hipStream_t stream)
{
  const float2* x = (const float2*)d_in[0];  // pre (2,4096,2)
  const float2* y = (const float2*)d_in[1];  // gt  (2,4096,2)
  float* ws = (float*)d_ws;

  k_init<<<64, BLOCK, 0, stream>>>(x, y, ws);

  const int nblocks = NB * NT * NT + 2 * NB * NT * NT;  // 2048 cross + 4096 self
  for (int s = 0; s < K_TOTAL; s++) {
    k_tiles<<<nblocks, BLOCK, 0, stream>>>(x, y, ws, s);
    k_combine<<<128, BLOCK, 0, stream>>>(ws, s);
  }
  k_reduce<<<1, 1024, 0, stream>>>(ws + P_OFF, (float*)d_out);
}